// Round 1
// baseline (752.390 us; speedup 1.0000x reference)
//
#include <hip/hip_runtime.h>
#include <hip/hip_bf16.h>

// Problem: out[B,S,O] = A[B,S,I] @ W[O,I]^T * scales[O] + bias[O]
// M = 8*2048 = 16384, N = 4096, K = 4096. Output fp32.
#define M_TOTAL 16384
#define N_TOTAL 4096
#define K_TOTAL 4096
#define BM 128
#define BN 128
#define BK 32

typedef __attribute__((ext_vector_type(8))) short bf16x8;
typedef __attribute__((ext_vector_type(4))) float f32x4;
typedef __attribute__((ext_vector_type(8))) unsigned short u16x8;

__device__ __forceinline__ unsigned short f32_to_bf16_rne(float f) {
  union { float f; unsigned u; } c; c.f = f;
  unsigned u = c.u;
  u += 0x7FFFu + ((u >> 16) & 1u);   // round-to-nearest-even
  return (unsigned short)(u >> 16);
}

// ---- conversion kernels (memory-bound; 16B/lane loads+stores) ----
__global__ void cvt_f32_bf16(const float* __restrict__ in, u16x8* __restrict__ out, int n8) {
  const int stride = gridDim.x * blockDim.x;
  for (int i = blockIdx.x * blockDim.x + threadIdx.x; i < n8; i += stride) {
    const float4* p = reinterpret_cast<const float4*>(in) + (size_t)2 * i;
    float4 v0 = p[0], v1 = p[1];
    u16x8 o;
    o[0] = f32_to_bf16_rne(v0.x); o[1] = f32_to_bf16_rne(v0.y);
    o[2] = f32_to_bf16_rne(v0.z); o[3] = f32_to_bf16_rne(v0.w);
    o[4] = f32_to_bf16_rne(v1.x); o[5] = f32_to_bf16_rne(v1.y);
    o[6] = f32_to_bf16_rne(v1.z); o[7] = f32_to_bf16_rne(v1.w);
    out[i] = o;
  }
}

__global__ void cvt_i32_bf16(const int* __restrict__ in, u16x8* __restrict__ out, int n8) {
  const int stride = gridDim.x * blockDim.x;
  for (int i = blockIdx.x * blockDim.x + threadIdx.x; i < n8; i += stride) {
    const int4* p = reinterpret_cast<const int4*>(in) + (size_t)2 * i;
    int4 v0 = p[0], v1 = p[1];
    u16x8 o;  // |w| <= 127: exact in bf16
    o[0] = f32_to_bf16_rne((float)v0.x); o[1] = f32_to_bf16_rne((float)v0.y);
    o[2] = f32_to_bf16_rne((float)v0.z); o[3] = f32_to_bf16_rne((float)v0.w);
    o[4] = f32_to_bf16_rne((float)v1.x); o[5] = f32_to_bf16_rne((float)v1.y);
    o[6] = f32_to_bf16_rne((float)v1.z); o[7] = f32_to_bf16_rne((float)v1.w);
    out[i] = o;
  }
}

// ---- m97-structure bf16 GEMM (B^T input), fused scale+bias epilogue ----
#define GLOAD_LDS16(gp, lp)                                                     \
  __builtin_amdgcn_global_load_lds(                                             \
      (const __attribute__((address_space(1))) void*)(gp),                      \
      (__attribute__((address_space(3))) void*)(lp), 16, 0, 0)

__global__ __launch_bounds__(256) void w8a16_gemm(
    const unsigned short* __restrict__ A,   // [M][K] bf16
    const unsigned short* __restrict__ Bt,  // [N][K] bf16 (W row-major)
    const float* __restrict__ scales, const float* __restrict__ bias,
    float* __restrict__ C) {
  __shared__ alignas(16) unsigned short sA[BM * BK];  // 8 KB, linear (gload_lds dest)
  __shared__ alignas(16) unsigned short sB[BN * BK];  // 8 KB

  const int tid = threadIdx.x;
  const int wave = tid >> 6;
  const int lane = tid & 63;
  const int bn = blockIdx.x;  // N tile
  const int bm = blockIdx.y;  // M tile
  const int wr = wave >> 1;   // 2x2 wave grid, 64x64 per wave
  const int wc = wave & 1;

  // staging: thread t covers tile elems [t*8, t*8+8) per instr; 2 instrs/tile
  const int srow = tid >> 2;         // t/4 (rows of 32 bf16 = 4 threads/row)
  const int scol = (tid & 3) * 8;
  const unsigned short* gA = A + (size_t)(bm * BM + srow) * K_TOTAL + scol;
  const unsigned short* gB = Bt + (size_t)(bn * BN + srow) * K_TOTAL + scol;

  // wave-uniform LDS dests (base + lane*16B is HW-implied)
  unsigned short* lA0 = sA + wave * 512;
  unsigned short* lA1 = sA + 2048 + wave * 512;
  unsigned short* lB0 = sB + wave * 512;
  unsigned short* lB1 = sB + 2048 + wave * 512;

  // fragment reads: A lane holds A[lane&15][(lane>>4)*8 + j], same for B cols
  const int fl = lane & 15;
  const int kb = (lane >> 4) * 8;
  const unsigned short* aRd = sA + (wr * 64 + fl) * BK + kb;
  const unsigned short* bRd = sB + (wc * 64 + fl) * BK + kb;

  f32x4 acc[4][4] = {};

  for (int kt = 0; kt < K_TOTAL / BK; ++kt) {
    GLOAD_LDS16(gA, lA0);
    GLOAD_LDS16(gA + 64 * K_TOTAL, lA1);
    GLOAD_LDS16(gB, lB0);
    GLOAD_LDS16(gB + 64 * K_TOTAL, lB1);
    gA += BK;
    gB += BK;
    __syncthreads();  // compiler emits vmcnt(0) drain before barrier

    bf16x8 af[4], bfr[4];
#pragma unroll
    for (int i = 0; i < 4; ++i)
      af[i] = *reinterpret_cast<const bf16x8*>(aRd + i * 16 * BK);
#pragma unroll
    for (int i = 0; i < 4; ++i)
      bfr[i] = *reinterpret_cast<const bf16x8*>(bRd + i * 16 * BK);
#pragma unroll
    for (int m = 0; m < 4; ++m)
#pragma unroll
      for (int n = 0; n < 4; ++n)
        acc[m][n] =
            __builtin_amdgcn_mfma_f32_16x16x32_bf16(af[m], bfr[n], acc[m][n], 0, 0, 0);
    __syncthreads();
  }

  // epilogue: C/D layout col=lane&15, row=(lane>>4)*4+reg (m89-verified)
  const int row0 = bm * BM + wr * 64 + (lane >> 4) * 4;
  const int col0 = bn * BN + wc * 64 + fl;
#pragma unroll
  for (int n = 0; n < 4; ++n) {
    const int col = col0 + n * 16;
    const float sc = scales[col];
    const float bi = bias[col];
#pragma unroll
    for (int m = 0; m < 4; ++m) {
      float* cp = C + (size_t)(row0 + m * 16) * N_TOTAL + col;
#pragma unroll
      for (int j = 0; j < 4; ++j) cp[(size_t)j * N_TOTAL] = fmaf(acc[m][n][j], sc, bi);
    }
  }
}

// ---- guarded fallback (only if d_ws is too small): correct but slow ----
__global__ void naive_gemm(const float* __restrict__ A, const int* __restrict__ W,
                           const float* __restrict__ scales, const float* __restrict__ bias,
                           float* __restrict__ C) {
  size_t idx = (size_t)blockIdx.x * blockDim.x + threadIdx.x;
  if (idx >= (size_t)M_TOTAL * N_TOTAL) return;
  const int n = (int)(idx % N_TOTAL);
  const size_t m = idx / N_TOTAL;
  const float* a = A + m * (size_t)K_TOTAL;
  const int* w = W + (size_t)n * K_TOTAL;
  float s = 0.f;
  for (int k = 0; k < K_TOTAL; ++k) s = fmaf(a[k], (float)w[k], s);
  C[idx] = fmaf(s, scales[n], bias[n]);
}

extern "C" void kernel_launch(void* const* d_in, const int* in_sizes, int n_in,
                              void* d_out, int out_size, void* d_ws, size_t ws_size,
                              hipStream_t stream) {
  const float* A = (const float*)d_in[0];        // [16384, 4096] f32
  const int* W = (const int*)d_in[1];            // [4096, 4096] int32 (int8 values)
  const float* scales = (const float*)d_in[2];   // [4096]
  const float* bias = (const float*)d_in[3];     // [4096]
  float* out = (float*)d_out;

  const size_t a_elems = (size_t)M_TOTAL * K_TOTAL;  // 67,108,864
  const size_t w_elems = (size_t)N_TOTAL * K_TOTAL;  // 16,777,216
  const size_t need = (a_elems + w_elems) * sizeof(unsigned short);  // 160 MB

  if (ws_size >= need) {
    unsigned short* A_bf = (unsigned short*)d_ws;
    unsigned short* W_bf = A_bf + a_elems;
    cvt_f32_bf16<<<2048, 256, 0, stream>>>(A, (u16x8*)A_bf, (int)(a_elems / 8));
    cvt_i32_bf16<<<2048, 256, 0, stream>>>(W, (u16x8*)W_bf, (int)(w_elems / 8));
    dim3 grid(N_TOTAL / BN, M_TOTAL / BM);
    w8a16_gemm<<<grid, 256, 0, stream>>>(A_bf, W_bf, scales, bias, out);
  } else {
    size_t total = (size_t)M_TOTAL * N_TOTAL;
    naive_gemm<<<(unsigned)((total + 255) / 256), 256, 0, stream>>>(A, W, scales, bias, out);
  }
}

// Round 2
// 557.465 us; speedup vs baseline: 1.3497x; 1.3497x over previous
//
#include <hip/hip_runtime.h>
#include <hip/hip_bf16.h>

// out[B,S,O] = A[B,S,I] @ W[O,I]^T * scales[O] + bias[O]
// M = 16384, N = 4096, K = 4096. Output fp32.
#define M_TOTAL 16384
#define N_TOTAL 4096
#define K_TOTAL 4096
#define NT (K_TOTAL / 64)  // 64 K-tiles of BK=64

typedef __attribute__((ext_vector_type(8))) short bf16x8;
typedef __attribute__((ext_vector_type(4))) float f32x4;
typedef __attribute__((ext_vector_type(8))) unsigned short u16x8;

__device__ __forceinline__ unsigned short f32_to_bf16_rne(float f) {
  union { float f; unsigned u; } c; c.f = f;
  unsigned u = c.u;
  u += 0x7FFFu + ((u >> 16) & 1u);
  return (unsigned short)(u >> 16);
}

__global__ void cvt_f32_bf16(const float* __restrict__ in, u16x8* __restrict__ out, int n8) {
  const int stride = gridDim.x * blockDim.x;
  for (int i = blockIdx.x * blockDim.x + threadIdx.x; i < n8; i += stride) {
    const float4* p = reinterpret_cast<const float4*>(in) + (size_t)2 * i;
    float4 v0 = p[0], v1 = p[1];
    u16x8 o;
    o[0] = f32_to_bf16_rne(v0.x); o[1] = f32_to_bf16_rne(v0.y);
    o[2] = f32_to_bf16_rne(v0.z); o[3] = f32_to_bf16_rne(v0.w);
    o[4] = f32_to_bf16_rne(v1.x); o[5] = f32_to_bf16_rne(v1.y);
    o[6] = f32_to_bf16_rne(v1.z); o[7] = f32_to_bf16_rne(v1.w);
    out[i] = o;
  }
}

__global__ void cvt_i32_bf16(const int* __restrict__ in, u16x8* __restrict__ out, int n8) {
  const int stride = gridDim.x * blockDim.x;
  for (int i = blockIdx.x * blockDim.x + threadIdx.x; i < n8; i += stride) {
    const int4* p = reinterpret_cast<const int4*>(in) + (size_t)2 * i;
    int4 v0 = p[0], v1 = p[1];
    u16x8 o;  // |w| <= 127: exact in bf16
    o[0] = f32_to_bf16_rne((float)v0.x); o[1] = f32_to_bf16_rne((float)v0.y);
    o[2] = f32_to_bf16_rne((float)v0.z); o[3] = f32_to_bf16_rne((float)v0.w);
    o[4] = f32_to_bf16_rne((float)v1.x); o[5] = f32_to_bf16_rne((float)v1.y);
    o[6] = f32_to_bf16_rne((float)v1.z); o[7] = f32_to_bf16_rne((float)v1.w);
    out[i] = o;
  }
}

// ======== 256x256 8-phase bf16 GEMM (T2+T3+T4+T5), B^T input ========
#define GLOAD_LDS16(gp, lp)                                                \
  __builtin_amdgcn_global_load_lds(                                        \
      (const __attribute__((address_space(1))) void*)(gp),                 \
      (__attribute__((address_space(3))) void*)(lp), 16, 0, 0)

#define BAR() asm volatile("s_barrier" ::: "memory")
#define LGKM0() asm volatile("s_waitcnt lgkmcnt(0)" ::: "memory")
#define VM(n) asm volatile("s_waitcnt vmcnt(" #n ")" ::: "memory")

// LDS map (131072 B): buf b: A_h0 [0,16K) A_h1 [16K,32K) B_h0 [32K,48K) B_h1 [48K,64K); buf1 at +64K.
// Half-tile = 128 rows x 64 bf16 cols, row stride 128 B.
// Swizzle: element (r,c) at byte r*128 + ((c*2) ^ ((r&7)<<4))  (involution, 16B-block permute).
// gload_lds writes linearly (wave w, inst q, lane l) -> off q*8192 + w*1024 + l*16, so the
// GLOBAL source is inverse-swizzled: row = q*64 + w*8 + (l>>3), colblk = ((l&7) ^ (l>>3))*8.

__global__ __launch_bounds__(512, 2) void w8a16_gemm256(
    const unsigned short* __restrict__ A,   // [M][K] bf16
    const unsigned short* __restrict__ Bt,  // [N][K] bf16
    const float* __restrict__ scales, const float* __restrict__ bias,
    float* __restrict__ C) {
  __shared__ alignas(16) unsigned char lds[131072];

  const int tid = threadIdx.x;
  const int w = tid >> 6, l = tid & 63;
  const int wr = w >> 2, wc = w & 3;  // 2x4 wave grid; per-wave 128x64 output
  const int bn = blockIdx.x, bm = blockIdx.y;

  // --- staging (pre-inverse-swizzled global source) ---
  const int rowq = tid >> 3;                     // = w*8 + (l>>3), 0..63
  const int colb = ((l & 7) ^ (l >> 3)) << 3;    // col block in elems
  const unsigned short* pA = A + (size_t)(bm * 256 + rowq) * K_TOTAL + colb;
  const unsigned short* pB = Bt + (size_t)(bn * 256 + rowq) * K_TOTAL + colb;
  unsigned char* const ldsp = lds;
  const int woff = w << 10;  // per-wave stage dest offset

#define SDA(b_, h_) (ldsp + (b_) * 65536 + (h_) * 16384 + woff)
#define SDB(b_, h_) (ldsp + (b_) * 65536 + 32768 + (h_) * 16384 + woff)
#define STAGE_A(b_, h_, t_)                                                   \
  do {                                                                        \
    GLOAD_LDS16(pA + (size_t)((h_) * 128) * K_TOTAL + (t_) * 64, SDA(b_, h_));\
    GLOAD_LDS16(pA + (size_t)((h_) * 128 + 64) * K_TOTAL + (t_) * 64,         \
                SDA(b_, h_) + 8192);                                          \
  } while (0)
#define STAGE_B(b_, h_, t_)                                                   \
  do {                                                                        \
    GLOAD_LDS16(pB + (size_t)((h_) * 128) * K_TOTAL + (t_) * 64, SDB(b_, h_));\
    GLOAD_LDS16(pB + (size_t)((h_) * 128 + 64) * K_TOTAL + (t_) * 64,         \
                SDB(b_, h_) + 8192);                                          \
  } while (0)

  // --- fragment read addressing (swizzled) ---
  // A-frag (m-frag fm, k-slot kk): row fm*16+(l&15), 16B at kk*64 + ((l>>4)<<4), swizzled by (l&7)<<4
  const int arow = ((l & 15) << 7) + ((((l >> 4) ^ (l & 7)) & 7) << 4);

  bf16x8 af[8];   // 4 m-frags x 2 k (current m-half)
  bf16x8 bfr[8];  // 4 n-frags x 2 k (whole tile, held across phases)
  f32x4 acc[8][4] = {{}};

#define RD_A(mh_)                                                             \
  do {                                                                        \
    const unsigned char* Ab_ = ldsp + bsel * 65536 + wr * 16384;              \
    _Pragma("unroll") for (int fm = 0; fm < 4; ++fm)                          \
        _Pragma("unroll") for (int kk = 0; kk < 2; ++kk)                      \
            af[fm * 2 + kk] = *(const bf16x8*)(Ab_ + ((mh_) * 4 + fm) * 2048 +\
                                               (arow ^ (kk << 6)));           \
  } while (0)
#define RD_B(nh_)                                                             \
  do {                                                                        \
    const unsigned char* Bb_ = ldsp + bsel * 65536 + 32768 +                  \
                               (wc >> 1) * 16384 + (wc & 1) * 8192;           \
    _Pragma("unroll") for (int fn = 0; fn < 2; ++fn)                          \
        _Pragma("unroll") for (int kk = 0; kk < 2; ++kk)                      \
            bfr[((nh_) * 2 + fn) * 2 + kk] =                                  \
                *(const bf16x8*)(Bb_ + ((nh_) * 2 + fn) * 2048 +              \
                                 (arow ^ (kk << 6)));                         \
  } while (0)
#define QUAD(mh_, nh_)                                                        \
  do {                                                                        \
    _Pragma("unroll") for (int m = 0; m < 4; ++m)                             \
        _Pragma("unroll") for (int n = 0; n < 2; ++n)                         \
            _Pragma("unroll") for (int kk = 0; kk < 2; ++kk)                  \
                acc[(mh_) * 4 + m][(nh_) * 2 + n] =                           \
                    __builtin_amdgcn_mfma_f32_16x16x32_bf16(                  \
                        af[m * 2 + kk], bfr[((nh_) * 2 + n) * 2 + kk],        \
                        acc[(mh_) * 4 + m][(nh_) * 2 + n], 0, 0, 0);          \
  } while (0)

  // --- prologue: tile0 complete + B halves of tile1; vmcnt(4) -> tile0 landed ---
  STAGE_A(0, 0, 0); STAGE_A(0, 1, 0);
  STAGE_B(0, 0, 0); STAGE_B(0, 1, 0);
  STAGE_B(1, 0, 1); STAGE_B(1, 1, 1);
  VM(4);
  BAR();

  // --- main loop: 4 phases / K-tile; stage A(t+1)@P1,P2 (other buf), B(t+2)@P3,P4 (this buf) ---
  // WAR: A halves of tile t-1 free after P3(t-1); B halves of tile t free after P2(t).
  // RAW: fence VM(4) at P4 leaves exactly B(t+2) (4 loads) in flight -> tile t+1 fully landed.
  for (int t = 0; t < NT; ++t) {
    const int bsel = t & 1;
    // P1: quadrant (m-half0, n-half0)
    RD_A(0); RD_B(0);
    if (t + 1 < NT) STAGE_A(bsel ^ 1, 0, t + 1);
    BAR(); LGKM0();
    __builtin_amdgcn_s_setprio(1); QUAD(0, 0); __builtin_amdgcn_s_setprio(0);
    BAR();
    // P2: (m-half0, n-half1)
    RD_B(1);
    if (t + 1 < NT) STAGE_A(bsel ^ 1, 1, t + 1);
    BAR(); LGKM0();
    __builtin_amdgcn_s_setprio(1); QUAD(0, 1); __builtin_amdgcn_s_setprio(0);
    BAR();
    // P3: (m-half1, n-half1)
    RD_A(1);
    if (t + 2 < NT) STAGE_B(bsel, 0, t + 2);
    BAR(); LGKM0();
    __builtin_amdgcn_s_setprio(1); QUAD(1, 1); __builtin_amdgcn_s_setprio(0);
    BAR();
    // P4: (m-half1, n-half0) — B-frags reused from registers
    if (t + 2 < NT) STAGE_B(bsel, 1, t + 2);
    BAR(); LGKM0();
    __builtin_amdgcn_s_setprio(1); QUAD(1, 0); __builtin_amdgcn_s_setprio(0);
    if (t < NT - 2) { VM(4); } else { VM(0); }
    BAR();
  }

  // --- epilogue: C/D layout col=lane&15, row=(lane>>4)*4+reg; fuse scale+bias ---
  const int row0 = bm * 256 + wr * 128 + ((l >> 4) << 2);
  const int col0 = bn * 256 + wc * 64 + (l & 15);
#pragma unroll
  for (int fn = 0; fn < 4; ++fn) {
    const int col = col0 + fn * 16;
    const float sc = scales[col];
    const float bi = bias[col];
#pragma unroll
    for (int fm = 0; fm < 8; ++fm) {
      float* cp = C + (size_t)(row0 + fm * 16) * N_TOTAL + col;
#pragma unroll
      for (int j = 0; j < 4; ++j) cp[(size_t)j * N_TOTAL] = fmaf(acc[fm][fn][j], sc, bi);
    }
  }
}

// ---- guarded fallback (only if d_ws too small) ----
__global__ void naive_gemm(const float* __restrict__ A, const int* __restrict__ W,
                           const float* __restrict__ scales, const float* __restrict__ bias,
                           float* __restrict__ C) {
  size_t idx = (size_t)blockIdx.x * blockDim.x + threadIdx.x;
  if (idx >= (size_t)M_TOTAL * N_TOTAL) return;
  const int n = (int)(idx % N_TOTAL);
  const size_t m = idx / N_TOTAL;
  const float* a = A + m * (size_t)K_TOTAL;
  const int* w = W + (size_t)n * K_TOTAL;
  float s = 0.f;
  for (int k = 0; k < K_TOTAL; ++k) s = fmaf(a[k], (float)w[k], s);
  C[idx] = fmaf(s, scales[n], bias[n]);
}

extern "C" void kernel_launch(void* const* d_in, const int* in_sizes, int n_in,
                              void* d_out, int out_size, void* d_ws, size_t ws_size,
                              hipStream_t stream) {
  const float* A = (const float*)d_in[0];
  const int* W = (const int*)d_in[1];
  const float* scales = (const float*)d_in[2];
  const float* bias = (const float*)d_in[3];
  float* out = (float*)d_out;

  const size_t a_elems = (size_t)M_TOTAL * K_TOTAL;
  const size_t w_elems = (size_t)N_TOTAL * K_TOTAL;
  const size_t need = (a_elems + w_elems) * sizeof(unsigned short);

  if (ws_size >= need) {
    unsigned short* A_bf = (unsigned short*)d_ws;
    unsigned short* W_bf = A_bf + a_elems;
    cvt_f32_bf16<<<2048, 256, 0, stream>>>(A, (u16x8*)A_bf, (int)(a_elems / 8));
    cvt_i32_bf16<<<2048, 256, 0, stream>>>(W, (u16x8*)W_bf, (int)(w_elems / 8));
    dim3 grid(N_TOTAL / 256, M_TOTAL / 256);  // (16, 64)
    w8a16_gemm256<<<grid, 512, 0, stream>>>(A_bf, W_bf, scales, bias, out);
  } else {
    size_t total = (size_t)M_TOTAL * N_TOTAL;
    naive_gemm<<<(unsigned)((total + 255) / 256), 256, 0, stream>>>(A, W, scales, bias, out);
  }
}